// Round 8
// baseline (161.893 us; speedup 1.0000x reference)
//
#include <hip/hip_runtime.h>
#include <hip/hip_bf16.h>

#define B_SZ 2048
#define H_SZ 200
#define EMB 128
#define HID 256
#define KW 160          // padded K in W1TB (130 real + zero pad)
#define NTILE 13        // 13 x 16 rows = 208 (200 real + 8 pad)

typedef short bf16x8 __attribute__((ext_vector_type(8)));
typedef float f32x4 __attribute__((ext_vector_type(4)));

__device__ __forceinline__ unsigned short bfc(float x) {
    unsigned u = __float_as_uint(x);
    u += 0x7FFFu + ((u >> 16) & 1u);
    return (unsigned short)(u >> 16);
}
__device__ __forceinline__ float bf2f(unsigned short h) {
    return __uint_as_float(((unsigned)h) << 16);
}

// W1 [130][256] fp32 -> W1TB [256][160] bf16 (k<130 real, 130..159 zero)
__global__ void prep_w1t(const float* __restrict__ W1, unsigned short* __restrict__ W1TB) {
    int i = blockIdx.x * 256 + threadIdx.x;      // 256*160
    int n = i / KW;
    int k = i - n * KW;
    float v = (k < 130) ? W1[k * HID + n] : 0.f;
    W1TB[i] = bfc(v);
}

// embed_history fp32 -> bf16 table
__global__ void prep_ehb(const float* __restrict__ eh, unsigned short* __restrict__ ehb) {
    size_t t = (size_t)blockIdx.x * 256 + threadIdx.x;
    const float4* src = (const float4*)eh + t * 2;
    float4 a = src[0], b = src[1];
    uint4 o;
    o.x = (unsigned)bfc(a.x) | ((unsigned)bfc(a.y) << 16);
    o.y = (unsigned)bfc(a.z) | ((unsigned)bfc(a.w) << 16);
    o.z = (unsigned)bfc(b.x) | ((unsigned)bfc(b.y) << 16);
    o.w = (unsigned)bfc(b.z) | ((unsigned)bfc(b.w) << 16);
    ((uint4*)ehb)[t] = o;
}

// One block per b. NO LDS staging of A: h-rows gathered straight into VGPRs
// as the MFMA B-operand (lane (lr,lq) loads 16B of row idxs[t*16+lr]).
// Barrier-free main loop (waves self-paced, 1-tile reg double buffer);
// cross-wave combine via red[] + one final barrier.
__global__ __launch_bounds__(512, 4) void attn_kernel(
    const int* __restrict__ history, const int* __restrict__ target,
    const float* __restrict__ td, const unsigned short* __restrict__ ehb,
    const float* __restrict__ et, const unsigned short* __restrict__ W1TB,
    const float* __restrict__ b1, const float* __restrict__ W2,
    const float* __restrict__ Wd, const float* __restrict__ bd,
    float* __restrict__ out)
{
    __shared__ float t_f32[EMB];
    __shared__ int idxs[224];
    __shared__ unsigned Adist[224];        // packed bf16 (d0,d1) per row
    __shared__ float red[NTILE][16][9];    // per-tile per-row per-wave partials
    __shared__ float u_arr[224];
    __shared__ float finred[16];

    const int tid = threadIdx.x;
    const int b   = blockIdx.x;
    const int tgt = target[b];

    // ---- phase 0: stage t row, dist sigmoid, history idx (single barrier) ----
    if (tid < 128) {
        t_f32[tid] = et[(size_t)tgt * EMB + tid];
    } else if (tid < 352) {
        const int g = tid - 128;           // 0..223
        int idx = 0; unsigned ad = 0u;
        if (g < H_SZ) {
            const int row = b * H_SZ + g;
            idx = history[row];
            float x0 = td[(size_t)row * 2 + 0] * 1000.f;
            float x1 = td[(size_t)row * 2 + 1] * 1000.f;
            float d0 = x0 * Wd[0] + x1 * Wd[2] + bd[0];
            float d1 = x0 * Wd[1] + x1 * Wd[3] + bd[1];
            d0 = 1.f / (1.f + expf(-d0));
            d1 = 1.f / (1.f + expf(-d1));
            ad = (unsigned)bfc(d0) | ((unsigned)bfc(d1) << 16);
        }
        idxs[g]  = idx;                    // pad rows gather row 0 harmlessly
        Adist[g] = ad;
    }
    __syncthreads();

    const int l  = tid & 63;
    const int w  = tid >> 6;
    const int lr = l & 15;
    const int lq = l >> 4;

    // ---- B_b = t-scaled W1 strips as MFMA A-operand frags (n = lane&15) ----
    bf16x8 bfrA[2][5];
    f32x4 b1v[2], w2v[2];
#pragma unroll
    for (int nt = 0; nt < 2; ++nt) {
        const int n = w * 32 + nt * 16 + lr;
        b1v[nt] = *reinterpret_cast<const f32x4*>(b1 + w * 32 + nt * 16 + lq * 4);
        w2v[nt] = *reinterpret_cast<const f32x4*>(W2 + w * 32 + nt * 16 + lq * 4);
#pragma unroll
        for (int ks = 0; ks < 4; ++ks) {
            bf16x8 wv = *reinterpret_cast<const bf16x8*>(W1TB + n * KW + ks * 32 + lq * 8);
            bf16x8 o;
#pragma unroll
            for (int j = 0; j < 8; ++j)
                o[j] = (short)bfc(bf2f((unsigned short)wv[j]) * t_f32[ks * 32 + lq * 8 + j]);
            bfrA[nt][ks] = o;
        }
        bfrA[nt][4] = *reinterpret_cast<const bf16x8*>(W1TB + n * KW + 128 + lq * 8);
    }

    // gather tile T's B-frags into HF (per-lane 16B contiguous loads)
#define LOADT(T, HF) {                                                         \
        const unsigned short* base_ = ehb + ((size_t)idxs[(T) * 16 + lr] << 7);\
        _Pragma("unroll")                                                      \
        for (int ks_ = 0; ks_ < 4; ++ks_)                                      \
            HF[ks_] = *reinterpret_cast<const bf16x8*>(base_ + ks_ * 32 + lq * 8); \
    }

    bf16x8 hf[2][4];
    LOADT(0, hf[0]);

    // ---- main loop: barrier-free, self-paced, reg double-buffered ----
#pragma unroll
    for (int t = 0; t < NTILE; ++t) {
        if (t + 1 < NTILE) LOADT(t + 1, hf[(t + 1) & 1]);

        // dist frag: k=128..135 slice -> (d0,d1,0,...) on lq==0 lanes
        uint4 dv = make_uint4((lq == 0) ? Adist[t * 16 + lr] : 0u, 0u, 0u, 0u);
        bf16x8 dfrag = *reinterpret_cast<bf16x8*>(&dv);

        f32x4 acc0 = (f32x4){0.f, 0.f, 0.f, 0.f};
        f32x4 acc1 = (f32x4){0.f, 0.f, 0.f, 0.f};
#pragma unroll
        for (int ks = 0; ks < 4; ++ks) {
            acc0 = __builtin_amdgcn_mfma_f32_16x16x32_bf16(bfrA[0][ks], hf[t & 1][ks], acc0, 0, 0, 0);
            acc1 = __builtin_amdgcn_mfma_f32_16x16x32_bf16(bfrA[1][ks], hf[t & 1][ks], acc1, 0, 0, 0);
        }
        acc0 = __builtin_amdgcn_mfma_f32_16x16x32_bf16(bfrA[0][4], dfrag, acc0, 0, 0, 0);
        acc1 = __builtin_amdgcn_mfma_f32_16x16x32_bf16(bfrA[1][4], dfrag, acc1, 0, 0, 0);

        // u = h.t for owned tile (wave t%8), from the same registers
        if (w == (t & 7)) {
            float ua = 0.f;
#pragma unroll
            for (int ks = 0; ks < 4; ++ks)
#pragma unroll
                for (int j = 0; j < 8; ++j)
                    ua += bf2f((unsigned short)hf[t & 1][ks][j]) * t_f32[ks * 32 + lq * 8 + j];
            ua += __shfl_xor(ua, 16);
            ua += __shfl_xor(ua, 32);
            if (l < 16) u_arr[t * 16 + lr] = ua;
        }

        // epilogue: lane-local relu*W2 over this wave's 8 n's, 2 shuffles
        float s = 0.f;
#pragma unroll
        for (int r = 0; r < 4; ++r) {
            s += fmaxf(acc0[r] + b1v[0][r], 0.f) * w2v[0][r];
            s += fmaxf(acc1[r] + b1v[1][r], 0.f) * w2v[1][r];
        }
        s += __shfl_xor(s, 16);
        s += __shfl_xor(s, 32);
        if (l < 16) red[t][lr][w] = s;
    }
#undef LOADT

    __syncthreads();

    // ---- finalize: attn -> exp/mask, pooled sigmoid ----
    float se = 0.f, su = 0.f;
    if (tid < NTILE * 16) {
        const int t = tid >> 4, m = tid & 15;
        float attn = 0.f;
#pragma unroll
        for (int ww = 0; ww < 8; ++ww) attn += red[t][m][ww];
        const bool valid = (tid < H_SZ) && (idxs[tid] != tgt);
        const float e = valid ? expf(attn) : 0.f;
        se = e;
        su = valid ? e * u_arr[tid] : 0.f;
    }
#pragma unroll
    for (int off = 1; off < 64; off <<= 1) {
        se += __shfl_xor(se, off);
        su += __shfl_xor(su, off);
    }
    if (l == 0) { finred[w * 2] = se; finred[w * 2 + 1] = su; }
    __syncthreads();
    if (tid == 0) {
        float SE = 0.f, SU = 0.f;
#pragma unroll
        for (int ww = 0; ww < 8; ++ww) { SE += finred[2 * ww]; SU += finred[2 * ww + 1]; }
        out[b] = 1.f / (1.f + expf(-SU / sqrtf(SE)));
    }
}

extern "C" void kernel_launch(void* const* d_in, const int* in_sizes, int n_in,
                              void* d_out, int out_size, void* d_ws, size_t ws_size,
                              hipStream_t stream) {
    const int*   history = (const int*)d_in[0];
    const int*   target  = (const int*)d_in[1];
    const float* td      = (const float*)d_in[4];
    const float* eh      = (const float*)d_in[5];
    const float* et      = (const float*)d_in[6];
    const float* W1      = (const float*)d_in[7];
    const float* b1      = (const float*)d_in[8];
    const float* W2      = (const float*)d_in[9];
    const float* Wd      = (const float*)d_in[10];
    const float* bd      = (const float*)d_in[11];
    float* out = (float*)d_out;

    char* ws = (char*)d_ws;
    unsigned short* W1TB = (unsigned short*)ws;            // 256*160*2 = 81,920 B
    unsigned short* ehb  = (unsigned short*)(ws + 81920);  // 25,600,000 B

    prep_w1t<<<HID * KW / 256, 256, 0, stream>>>(W1, W1TB);
    prep_ehb<<<1600000 / 256, 256, 0, stream>>>(eh, ehb);
    attn_kernel<<<B_SZ, 512, 0, stream>>>(history, target, td, ehb, et, W1TB,
                                          b1, W2, Wd, bd, out);
}

// Round 9
// 145.989 us; speedup vs baseline: 1.1089x; 1.1089x over previous
//
#include <hip/hip_runtime.h>
#include <hip/hip_bf16.h>

#define B_SZ 2048
#define H_SZ 200
#define BH (B_SZ * H_SZ)         // 409600
#define EMB 128
#define HID 256
#define KW 160                   // padded K in W1TB (130 real + zero pad)
#define NBIN 100352              // 100000 items padded to 98*1024
#define NSCB 98                  // scan blocks

typedef short bf16x8 __attribute__((ext_vector_type(8)));
typedef float f32x4 __attribute__((ext_vector_type(4)));

__device__ __forceinline__ unsigned short bfc(float x) {
    unsigned u = __float_as_uint(x);
    u += 0x7FFFu + ((u >> 16) & 1u);
    return (unsigned short)(u >> 16);
}
__device__ __forceinline__ float bf2f(unsigned short h) {
    return __uint_as_float(((unsigned)h) << 16);
}

// ---------------- sort pipeline ----------------
__global__ void k_zero(unsigned* __restrict__ hist) {
    int i = blockIdx.x * 512 + threadIdx.x;
    if (i < NBIN) hist[i] = 0u;
}
__global__ void k_hist(const int* __restrict__ history, unsigned* __restrict__ hist) {
    int i = blockIdx.x * 512 + threadIdx.x;          // 409600
    atomicAdd(&hist[history[i]], 1u);
}
// 98 blocks x 1024: in-place exclusive scan within block, block total -> bsum
__global__ void k_scan1(unsigned* __restrict__ hist, unsigned* __restrict__ bsum) {
    __shared__ unsigned wsum[16];
    const int tid = threadIdx.x;
    const int i = blockIdx.x * 1024 + tid;
    const int lane = tid & 63, wid = tid >> 6;
    unsigned v = hist[i];
    unsigned incl = v;
#pragma unroll
    for (int off = 1; off < 64; off <<= 1) {
        unsigned t = __shfl_up(incl, off);
        if (lane >= off) incl += t;
    }
    if (lane == 63) wsum[wid] = incl;
    __syncthreads();
    if (tid == 0) {
        unsigned run = 0;
#pragma unroll
        for (int k = 0; k < 16; ++k) { unsigned t = wsum[k]; wsum[k] = run; run += t; }
        bsum[blockIdx.x] = run;
    }
    __syncthreads();
    hist[i] = incl - v + wsum[wid];
}
__global__ void k_scan2(unsigned* __restrict__ bsum) {
    if (threadIdx.x == 0 && blockIdx.x == 0) {
        unsigned run = 0;
        for (int k = 0; k < NSCB; ++k) { unsigned t = bsum[k]; bsum[k] = run; run += t; }
    }
}
__global__ void k_add(unsigned* __restrict__ hist, const unsigned* __restrict__ bsum) {
    int i = blockIdx.x * 512 + threadIdx.x;
    if (i < NBIN) hist[i] += bsum[i >> 10];
}
__global__ void k_scatter(const int* __restrict__ history, unsigned* __restrict__ hist,
                          unsigned* __restrict__ sidx, unsigned* __restrict__ srow) {
    int i = blockIdx.x * 512 + threadIdx.x;          // 409600
    int idx = history[i];
    unsigned pos = atomicAdd(&hist[idx], 1u);
    unsigned b = (unsigned)i / 200u;
    unsigned h = (unsigned)i - b * 200u;
    sidx[pos] = (unsigned)idx;
    srow[pos] = (b << 8) | h;
}

// W1 [130][256] fp32 -> W1TB [256][160] bf16 (k<130 real, 130..159 zero)
__global__ void prep_w1t(const float* __restrict__ W1, unsigned short* __restrict__ W1TB) {
    int i = blockIdx.x * 256 + threadIdx.x;          // 256*160
    int n = i / KW;
    int k = i - n * KW;
    float v = (k < 130) ? W1[k * HID + n] : 0.f;
    W1TB[i] = bfc(v);
}

// ---------------- main: 128 sorted rows per block ----------------
__global__ __launch_bounds__(512, 4) void attn_main(
    const unsigned* __restrict__ sidx, const unsigned* __restrict__ srow,
    const int* __restrict__ target, const float* __restrict__ td,
    const float* __restrict__ eh, const float* __restrict__ et,
    const unsigned short* __restrict__ W1TB, const float* __restrict__ b1,
    const float* __restrict__ W2, const float* __restrict__ Wd,
    const float* __restrict__ bd,
    float* __restrict__ expA, float* __restrict__ eu)
{
    __shared__ __align__(16) unsigned short prod[8][16][128];  // 32 KB, chunk-swizzled
    __shared__ float red[8][16][9];
    __shared__ unsigned Adist[128];       // packed bf16 (d0,d1) per row
    __shared__ unsigned sidx_s[128], srow_s[128], tgt_s[128];
    __shared__ float u_arr[128];

    const int tid = threadIdx.x;
    const int base = blockIdx.x * 128;

    // ---- phase 0: stage row meta, dist sigmoid ----
    if (tid < 128) {
        unsigned si = sidx[base + tid];
        unsigned sr = srow[base + tid];
        sidx_s[tid] = si;
        srow_s[tid] = sr;
        const unsigned b = sr >> 8, h = sr & 255u;
        const unsigned orig = b * 200u + h;
        tgt_s[tid] = (unsigned)target[b];
        float x0 = td[(size_t)orig * 2 + 0] * 1000.f;
        float x1 = td[(size_t)orig * 2 + 1] * 1000.f;
        float d0 = x0 * Wd[0] + x1 * Wd[2] + bd[0];
        float d1 = x0 * Wd[1] + x1 * Wd[3] + bd[1];
        d0 = 1.f / (1.f + expf(-d0));
        d1 = 1.f / (1.f + expf(-d1));
        Adist[tid] = (unsigned)bfc(d0) | ((unsigned)bfc(d1) << 16);
    }
    __syncthreads();

    // ---- phase 1: stage product tile h*t (fp32 mul -> bf16), u for free ----
    {
        const int r = tid >> 2;          // row in block (0..127)
        const int c = tid & 3;           // 32-elem chunk
        const unsigned b = srow_s[r] >> 8;
        const float4* hp = (const float4*)(eh + (size_t)sidx_s[r] * EMB + c * 32);
        const float4* tp = (const float4*)(et + (size_t)b * EMB + c * 32);
        float su = 0.f;
        unsigned pk[16];
#pragma unroll
        for (int j = 0; j < 8; ++j) {
            float4 hv = hp[j];
            float4 tv = tp[j];
            float p0 = hv.x * tv.x, p1 = hv.y * tv.y;
            float p2 = hv.z * tv.z, p3 = hv.w * tv.w;
            su += (p0 + p1) + (p2 + p3);
            pk[2 * j]     = (unsigned)bfc(p0) | ((unsigned)bfc(p1) << 16);
            pk[2 * j + 1] = (unsigned)bfc(p2) | ((unsigned)bfc(p3) << 16);
        }
        // write 4 x 16B chunks, chunk-XOR swizzle within row
        unsigned short* rowp = &prod[r >> 4][r & 15][0];
#pragma unroll
        for (int j = 0; j < 4; ++j) {
            const int phys = ((c * 4 + j) ^ (r & 7)) * 8;
            *reinterpret_cast<uint4*>(rowp + phys) =
                make_uint4(pk[4 * j], pk[4 * j + 1], pk[4 * j + 2], pk[4 * j + 3]);
        }
        su += __shfl_xor(su, 1);
        su += __shfl_xor(su, 2);
        if (c == 0) u_arr[r] = su;
    }

    const int l  = tid & 63;
    const int w  = tid >> 6;
    const int lr = l & 15;
    const int lq = l >> 4;

    // ---- W1 strips as MFMA A-operand frags (raw, n = w*32 + nt*16 + lr) ----
    bf16x8 bfrA[2][5];
    f32x4 b1v[2], w2v[2];
#pragma unroll
    for (int nt = 0; nt < 2; ++nt) {
        const int n = w * 32 + nt * 16 + lr;
        b1v[nt] = *reinterpret_cast<const f32x4*>(b1 + w * 32 + nt * 16 + lq * 4);
        w2v[nt] = *reinterpret_cast<const f32x4*>(W2 + w * 32 + nt * 16 + lq * 4);
#pragma unroll
        for (int ks = 0; ks < 4; ++ks)
            bfrA[nt][ks] = *reinterpret_cast<const bf16x8*>(W1TB + n * KW + ks * 32 + lq * 8);
        bfrA[nt][4] = *reinterpret_cast<const bf16x8*>(W1TB + n * KW + 128 + lq * 8);
    }
    __syncthreads();

    // ---- phase 2: 8 waves x 8 tiles, MFMA from LDS, no per-tile barrier ----
#pragma unroll
    for (int t = 0; t < 8; ++t) {
        uint4 dv = make_uint4((lq == 0) ? Adist[t * 16 + lr] : 0u, 0u, 0u, 0u);
        bf16x8 dfrag = *reinterpret_cast<bf16x8*>(&dv);

        f32x4 acc0 = (f32x4){0.f, 0.f, 0.f, 0.f};
        f32x4 acc1 = (f32x4){0.f, 0.f, 0.f, 0.f};
#pragma unroll
        for (int ks = 0; ks < 4; ++ks) {
            const bf16x8 hf = *reinterpret_cast<const bf16x8*>(
                &prod[t][lr][(((ks * 4 + lq) ^ (lr & 7)) * 8)]);
            acc0 = __builtin_amdgcn_mfma_f32_16x16x32_bf16(bfrA[0][ks], hf, acc0, 0, 0, 0);
            acc1 = __builtin_amdgcn_mfma_f32_16x16x32_bf16(bfrA[1][ks], hf, acc1, 0, 0, 0);
        }
        acc0 = __builtin_amdgcn_mfma_f32_16x16x32_bf16(bfrA[0][4], dfrag, acc0, 0, 0, 0);
        acc1 = __builtin_amdgcn_mfma_f32_16x16x32_bf16(bfrA[1][4], dfrag, acc1, 0, 0, 0);

        float s = 0.f;
#pragma unroll
        for (int r = 0; r < 4; ++r) {
            s += fmaxf(acc0[r] + b1v[0][r], 0.f) * w2v[0][r];
            s += fmaxf(acc1[r] + b1v[1][r], 0.f) * w2v[1][r];
        }
        s += __shfl_xor(s, 16);
        s += __shfl_xor(s, 32);
        if (l < 16) red[t][lr][w] = s;
    }
    __syncthreads();

    // ---- phase 3: e, e*u scatter-write ----
    if (tid < 128) {
        const int t = tid >> 4, m = tid & 15;
        float attn = 0.f;
#pragma unroll
        for (int ww = 0; ww < 8; ++ww) attn += red[t][m][ww];
        const unsigned sr = srow_s[tid];
        const unsigned b = sr >> 8, h = sr & 255u;
        const unsigned orig = b * 200u + h;
        const bool valid = (sidx_s[tid] != tgt_s[tid]);
        const float e = valid ? expf(attn) : 0.f;
        expA[orig] = e;
        eu[orig]   = e * u_arr[tid];
    }
}

// per-b: pred = sum(eu) / sqrt(sum(e)); out = sigmoid(pred)
__global__ void finalize_kernel(const float* __restrict__ expA,
                                const float* __restrict__ eu,
                                float* __restrict__ out)
{
    const int l = threadIdx.x & 63;
    const int w = threadIdx.x >> 6;
    const int b = blockIdx.x * 4 + w;
    const float* ea = expA + b * H_SZ;
    const float* ee = eu + b * H_SZ;
    float se = 0.f, su = 0.f;
    for (int h = l; h < H_SZ; h += 64) {
        se += ea[h];
        su += ee[h];
    }
#pragma unroll
    for (int off = 32; off; off >>= 1) {
        se += __shfl_xor(se, off);
        su += __shfl_xor(su, off);
    }
    if (l == 0) out[b] = 1.f / (1.f + expf(-su / sqrtf(se)));
}

extern "C" void kernel_launch(void* const* d_in, const int* in_sizes, int n_in,
                              void* d_out, int out_size, void* d_ws, size_t ws_size,
                              hipStream_t stream) {
    const int*   history = (const int*)d_in[0];
    const int*   target  = (const int*)d_in[1];
    const float* td      = (const float*)d_in[4];
    const float* eh      = (const float*)d_in[5];
    const float* et      = (const float*)d_in[6];
    const float* W1      = (const float*)d_in[7];
    const float* b1      = (const float*)d_in[8];
    const float* W2      = (const float*)d_in[9];
    const float* Wd      = (const float*)d_in[10];
    const float* bd      = (const float*)d_in[11];
    float* out = (float*)d_out;

    char* ws = (char*)d_ws;
    unsigned short* W1TB = (unsigned short*)ws;                    //    81,920 B
    unsigned* hist = (unsigned*)(ws + 81920);                      //   401,408 B
    unsigned* bsum = (unsigned*)(ws + 81920 + 401408);             //       512 B
    unsigned* sidx = (unsigned*)(ws + 81920 + 401920);             // 1,638,400 B
    unsigned* srow = (unsigned*)(ws + 81920 + 401920 + 1638400);   // 1,638,400 B
    float* expA = (float*)(ws + 81920 + 401920 + 2 * 1638400);     // 1,638,400 B
    float* eu   = (float*)(ws + 81920 + 401920 + 3 * 1638400);     // 1,638,400 B

    prep_w1t<<<HID * KW / 256, 256, 0, stream>>>(W1, W1TB);
    k_zero<<<(NBIN + 511) / 512, 512, 0, stream>>>(hist);
    k_hist<<<BH / 512, 512, 0, stream>>>(history, hist);
    k_scan1<<<NSCB, 1024, 0, stream>>>(hist, bsum);
    k_scan2<<<1, 64, 0, stream>>>(bsum);
    k_add<<<(NBIN + 511) / 512, 512, 0, stream>>>(hist, bsum);
    k_scatter<<<BH / 512, 512, 0, stream>>>(history, hist, sidx, srow);
    attn_main<<<BH / 128, 512, 0, stream>>>(sidx, srow, target, td, eh, et,
                                            W1TB, b1, W2, Wd, bd, expA, eu);
    finalize_kernel<<<B_SZ / 4, 256, 0, stream>>>(expA, eu, out);
}

// Round 11
// 131.808 us; speedup vs baseline: 1.2282x; 1.1076x over previous
//
#include <hip/hip_runtime.h>
#include <hip/hip_bf16.h>

#define B_SZ 2048
#define H_SZ 200
#define BH (B_SZ * H_SZ)         // 409600
#define EMB 128
#define HID 256
#define KW 160                   // padded K in W1TB (130 real + zero pad)
#define NBIN 100352              // 100000 items padded to 98*1024
#define NSCB 98                  // scan blocks
#define PSTR 144                 // prod row stride in shorts (288B, 16B-aligned)

typedef short bf16x8 __attribute__((ext_vector_type(8)));
typedef float f32x4 __attribute__((ext_vector_type(4)));

__device__ __forceinline__ unsigned short bfc(float x) {
    unsigned u = __float_as_uint(x);
    u += 0x7FFFu + ((u >> 16) & 1u);
    return (unsigned short)(u >> 16);
}
__device__ __forceinline__ float bf2f(unsigned short h) {
    return __uint_as_float(((unsigned)h) << 16);
}

// ---------------- prep kernels ----------------
__global__ void prep_w1t(const float* __restrict__ W1, unsigned short* __restrict__ W1TB) {
    int i = blockIdx.x * 256 + threadIdx.x;          // 256*160
    int n = i / KW;
    int k = i - n * KW;
    float v = (k < 130) ? W1[k * HID + n] : 0.f;
    W1TB[i] = bfc(v);
}
__global__ void prep_tdb(const int* __restrict__ target, const float* __restrict__ et,
                         unsigned short* __restrict__ tdb) {
    int i = blockIdx.x * 256 + threadIdx.x;          // 2048*128
    int b = i >> 7, e = i & 127;
    tdb[i] = bfc(et[(size_t)target[b] * EMB + e]);
}
__global__ void prep_ehb(const float* __restrict__ eh, unsigned short* __restrict__ ehb) {
    size_t t = (size_t)blockIdx.x * 256 + threadIdx.x;
    const float4* src = (const float4*)eh + t * 2;
    float4 a = src[0], b = src[1];
    uint4 o;
    o.x = (unsigned)bfc(a.x) | ((unsigned)bfc(a.y) << 16);
    o.y = (unsigned)bfc(a.z) | ((unsigned)bfc(a.w) << 16);
    o.z = (unsigned)bfc(b.x) | ((unsigned)bfc(b.y) << 16);
    o.w = (unsigned)bfc(b.z) | ((unsigned)bfc(b.w) << 16);
    ((uint4*)ehb)[t] = o;
}

// ---------------- sort pipeline ----------------
__global__ void k_zero(unsigned* __restrict__ hist) {
    int i = blockIdx.x * 512 + threadIdx.x;
    if (i < NBIN) hist[i] = 0u;
}
__global__ void k_hist(const int* __restrict__ history, unsigned* __restrict__ hist) {
    int i = blockIdx.x * 512 + threadIdx.x;          // 409600
    atomicAdd(&hist[history[i]], 1u);
}
__global__ void k_scan1(unsigned* __restrict__ hist, unsigned* __restrict__ bsum) {
    __shared__ unsigned wsum[16];
    const int tid = threadIdx.x;
    const int i = blockIdx.x * 1024 + tid;
    const int lane = tid & 63, wid = tid >> 6;
    unsigned v = hist[i];
    unsigned incl = v;
#pragma unroll
    for (int off = 1; off < 64; off <<= 1) {
        unsigned t = __shfl_up(incl, off);
        if (lane >= off) incl += t;
    }
    if (lane == 63) wsum[wid] = incl;
    __syncthreads();
    if (tid == 0) {
        unsigned run = 0;
#pragma unroll
        for (int k = 0; k < 16; ++k) { unsigned t = wsum[k]; wsum[k] = run; run += t; }
        bsum[blockIdx.x] = run;
    }
    __syncthreads();
    hist[i] = incl - v + wsum[wid];
}
__global__ void k_scan2(unsigned* __restrict__ bsum) {
    if (threadIdx.x == 0 && blockIdx.x == 0) {
        unsigned run = 0;
        for (int k = 0; k < NSCB; ++k) { unsigned t = bsum[k]; bsum[k] = run; run += t; }
    }
}
__global__ void k_add(unsigned* __restrict__ hist, const unsigned* __restrict__ bsum) {
    int i = blockIdx.x * 512 + threadIdx.x;
    if (i < NBIN) hist[i] += bsum[i >> 10];
}
// emits: meta[pos] = (b<<18)|(valid<<17)|item ; sdist[pos] = packed bf16 (d0,d1);
//        inv[i] = pos   (all random small reads done HERE, coalesced)
__global__ void k_scatter(const int* __restrict__ history, const int* __restrict__ target,
                          const float* __restrict__ td, const float* __restrict__ Wd,
                          const float* __restrict__ bd, unsigned* __restrict__ hist,
                          unsigned* __restrict__ meta, unsigned* __restrict__ sdist,
                          unsigned* __restrict__ inv) {
    int i = blockIdx.x * 512 + threadIdx.x;          // 409600
    int idx = history[i];
    int b = i / 200;
    unsigned pos = atomicAdd(&hist[idx], 1u);
    int tgt = target[b];
    float x0 = td[(size_t)i * 2 + 0] * 1000.f;
    float x1 = td[(size_t)i * 2 + 1] * 1000.f;
    float d0 = x0 * Wd[0] + x1 * Wd[2] + bd[0];
    float d1 = x0 * Wd[1] + x1 * Wd[3] + bd[1];
    d0 = 1.f / (1.f + expf(-d0));
    d1 = 1.f / (1.f + expf(-d1));
    meta[pos]  = ((unsigned)b << 18) | ((idx != tgt) ? (1u << 17) : 0u) | (unsigned)idx;
    sdist[pos] = (unsigned)bfc(d0) | ((unsigned)bfc(d1) << 16);
    inv[i] = pos;
}

// ---------------- main: 128 sorted rows per block ----------------
// sE aliases meta, sU aliases sdist (each block reads its own range in phase 0,
// writes the same range in phase 3; no cross-block access).
template<bool BF16E>
__global__ __launch_bounds__(512, 4) void attn_main(
    const unsigned* __restrict__ meta_g, const unsigned* __restrict__ sdist_g,
    const float* __restrict__ eh, const unsigned short* __restrict__ ehb,
    const unsigned short* __restrict__ tdb, const unsigned short* __restrict__ W1TB,
    const float* __restrict__ b1, const float* __restrict__ W2,
    float* __restrict__ sE, float* __restrict__ sU)
{
    __shared__ __align__(16) unsigned short prod[8 * 16 * PSTR];  // 36.9 KB
    __shared__ float red[8][16][9];
    __shared__ unsigned meta_s[128];
    __shared__ unsigned Adist[128];
    __shared__ float u_arr[128];

    const int tid = threadIdx.x;
    const int base = blockIdx.x * 128;

    // ---- phase 0: coalesced meta ----
    if (tid < 128) {
        meta_s[tid] = meta_g[base + tid];
        Adist[tid]  = sdist_g[base + tid];
    }
    __syncthreads();

    const int l  = tid & 63;
    const int w  = tid >> 6;
    const int lr = l & 15;
    const int lq = l >> 4;

    // ---- phase 1: product tile (h*t -> bf16 in LDS), u for free ----
    {
        const int r = tid >> 2;          // row in block (0..127)
        const int c = tid & 3;           // 32-elem chunk
        const unsigned m = meta_s[r];
        const unsigned item = m & 0x1FFFFu;
        const unsigned b = m >> 18;
        // load-all-then-compute
        bf16x8 tb[4];
#pragma unroll
        for (int j = 0; j < 4; ++j)
            tb[j] = *reinterpret_cast<const bf16x8*>(tdb + ((size_t)b << 7) + c * 32 + j * 8);

        float p[32];
        if (BF16E) {
            bf16x8 hb[4];
#pragma unroll
            for (int j = 0; j < 4; ++j)
                hb[j] = *reinterpret_cast<const bf16x8*>(ehb + ((size_t)item << 7) + c * 32 + j * 8);
#pragma unroll
            for (int j = 0; j < 4; ++j)
#pragma unroll
                for (int e = 0; e < 8; ++e)
                    p[j * 8 + e] = bf2f((unsigned short)hb[j][e]) * bf2f((unsigned short)tb[j][e]);
        } else {
            float4 hf[8];
#pragma unroll
            for (int j = 0; j < 8; ++j)
                hf[j] = *((const float4*)(eh + ((size_t)item << 7) + c * 32) + j);
#pragma unroll
            for (int j = 0; j < 8; ++j) {
                p[j * 4 + 0] = hf[j].x * bf2f((unsigned short)tb[j >> 1][(j & 1) * 4 + 0]);
                p[j * 4 + 1] = hf[j].y * bf2f((unsigned short)tb[j >> 1][(j & 1) * 4 + 1]);
                p[j * 4 + 2] = hf[j].z * bf2f((unsigned short)tb[j >> 1][(j & 1) * 4 + 2]);
                p[j * 4 + 3] = hf[j].w * bf2f((unsigned short)tb[j >> 1][(j & 1) * 4 + 3]);
            }
        }
        // pack + sum (R9-proven): pk[j] holds elements 2j, 2j+1
        float su = 0.f;
        unsigned pk[16];
#pragma unroll
        for (int j = 0; j < 16; ++j) {
            float p0 = p[2 * j], p1 = p[2 * j + 1];
            su += p0 + p1;
            pk[j] = (unsigned)bfc(p0) | ((unsigned)bfc(p1) << 16);
        }
        // write 4 x 16B chunks at XOR-swizzled slots (all 16 chunks/row covered)
        unsigned short* rowp = prod + r * PSTR;
#pragma unroll
        for (int j = 0; j < 4; ++j) {
            const int phys = ((c * 4 + j) ^ (r & 7)) * 8;
            *reinterpret_cast<uint4*>(rowp + phys) =
                make_uint4(pk[4 * j + 0], pk[4 * j + 1], pk[4 * j + 2], pk[4 * j + 3]);
        }
        su += __shfl_xor(su, 1);
        su += __shfl_xor(su, 2);
        if (c == 0) u_arr[r] = su;
    }

    // ---- W1 strips as MFMA A-operand frags ----
    bf16x8 bfrA[2][5];
    f32x4 b1v[2], w2v[2];
#pragma unroll
    for (int nt = 0; nt < 2; ++nt) {
        const int n = w * 32 + nt * 16 + lr;
        b1v[nt] = *reinterpret_cast<const f32x4*>(b1 + w * 32 + nt * 16 + lq * 4);
        w2v[nt] = *reinterpret_cast<const f32x4*>(W2 + w * 32 + nt * 16 + lq * 4);
#pragma unroll
        for (int ks = 0; ks < 4; ++ks)
            bfrA[nt][ks] = *reinterpret_cast<const bf16x8*>(W1TB + n * KW + ks * 32 + lq * 8);
        bfrA[nt][4] = *reinterpret_cast<const bf16x8*>(W1TB + n * KW + 128 + lq * 8);
    }
    __syncthreads();

    // ---- phase 2: 8 waves x 8 tiles, MFMA from LDS ----
#pragma unroll
    for (int t = 0; t < 8; ++t) {
        uint4 dv = make_uint4((lq == 0) ? Adist[t * 16 + lr] : 0u, 0u, 0u, 0u);
        bf16x8 dfrag = *reinterpret_cast<bf16x8*>(&dv);
        const unsigned short* rowp = prod + (t * 16 + lr) * PSTR;

        f32x4 acc0 = (f32x4){0.f, 0.f, 0.f, 0.f};
        f32x4 acc1 = (f32x4){0.f, 0.f, 0.f, 0.f};
#pragma unroll
        for (int ks = 0; ks < 4; ++ks) {
            const bf16x8 hf = *reinterpret_cast<const bf16x8*>(
                rowp + (((ks * 4 + lq) ^ (lr & 7)) * 8));
            acc0 = __builtin_amdgcn_mfma_f32_16x16x32_bf16(bfrA[0][ks], hf, acc0, 0, 0, 0);
            acc1 = __builtin_amdgcn_mfma_f32_16x16x32_bf16(bfrA[1][ks], hf, acc1, 0, 0, 0);
        }
        acc0 = __builtin_amdgcn_mfma_f32_16x16x32_bf16(bfrA[0][4], dfrag, acc0, 0, 0, 0);
        acc1 = __builtin_amdgcn_mfma_f32_16x16x32_bf16(bfrA[1][4], dfrag, acc1, 0, 0, 0);

        float s = 0.f;
#pragma unroll
        for (int r = 0; r < 4; ++r) {
            s += fmaxf(acc0[r] + b1v[0][r], 0.f) * w2v[0][r];
            s += fmaxf(acc1[r] + b1v[1][r], 0.f) * w2v[1][r];
        }
        s += __shfl_xor(s, 16);
        s += __shfl_xor(s, 32);
        if (l < 16) red[t][lr][w] = s;
    }
    __syncthreads();

    // ---- phase 3: coalesced e, e*u at sorted positions ----
    if (tid < 128) {
        const int t = tid >> 4, m = tid & 15;
        float attn = 0.f;
#pragma unroll
        for (int ww = 0; ww < 8; ++ww) attn += red[t][m][ww];
        const bool valid = (meta_s[tid] >> 17) & 1u;
        const float e = valid ? expf(attn) : 0.f;
        sE[base + tid] = e;
        sU[base + tid] = e * u_arr[tid];
    }
}

// per-b: gather via inv (coalesced inv read, L2-resident sE/sU)
__global__ void finalize_kernel(const unsigned* __restrict__ inv,
                                const float* __restrict__ sE,
                                const float* __restrict__ sU,
                                float* __restrict__ out)
{
    const int l = threadIdx.x & 63;
    const int w = threadIdx.x >> 6;
    const int b = blockIdx.x * 4 + w;
    float se = 0.f, su = 0.f;
    for (int h = l; h < H_SZ; h += 64) {
        unsigned pos = inv[b * H_SZ + h];
        se += sE[pos];
        su += sU[pos];
    }
#pragma unroll
    for (int off = 32; off; off >>= 1) {
        se += __shfl_xor(se, off);
        su += __shfl_xor(su, off);
    }
    if (l == 0) out[b] = 1.f / (1.f + expf(-su / sqrtf(se)));
}

extern "C" void kernel_launch(void* const* d_in, const int* in_sizes, int n_in,
                              void* d_out, int out_size, void* d_ws, size_t ws_size,
                              hipStream_t stream) {
    const int*   history = (const int*)d_in[0];
    const int*   target  = (const int*)d_in[1];
    const float* td      = (const float*)d_in[4];
    const float* eh      = (const float*)d_in[5];
    const float* et      = (const float*)d_in[6];
    const float* W1      = (const float*)d_in[7];
    const float* b1      = (const float*)d_in[8];
    const float* W2      = (const float*)d_in[9];
    const float* Wd      = (const float*)d_in[10];
    const float* bd      = (const float*)d_in[11];
    float* out = (float*)d_out;

    char* ws = (char*)d_ws;
    unsigned short* W1TB = (unsigned short*)(ws);                  //    81,920 B
    unsigned short* tdb  = (unsigned short*)(ws + 81920);          //   524,288 B
    unsigned* hist  = (unsigned*)(ws + 606208);                    //   401,408 B
    unsigned* bsum  = (unsigned*)(ws + 1007616);                   //       512 B
    unsigned* meta  = (unsigned*)(ws + 1008128);                   // 1,638,400 B (aliased by sE)
    unsigned* sdist = (unsigned*)(ws + 2646528);                   // 1,638,400 B (aliased by sU)
    unsigned* inv   = (unsigned*)(ws + 4284928);                   // 1,638,400 B
    unsigned short* ehb = (unsigned short*)(ws + 5923328);         // 25,600,000 B
    const bool useBf16 = ws_size >= 31523328ull;

    prep_w1t<<<HID * KW / 256, 256, 0, stream>>>(W1, W1TB);
    prep_tdb<<<B_SZ * EMB / 256, 256, 0, stream>>>(target, et, tdb);
    if (useBf16) prep_ehb<<<1600000 / 256, 256, 0, stream>>>(eh, ehb);
    k_zero<<<(NBIN + 511) / 512, 512, 0, stream>>>(hist);
    k_hist<<<BH / 512, 512, 0, stream>>>(history, hist);
    k_scan1<<<NSCB, 1024, 0, stream>>>(hist, bsum);
    k_scan2<<<1, 64, 0, stream>>>(bsum);
    k_add<<<(NBIN + 511) / 512, 512, 0, stream>>>(hist, bsum);
    k_scatter<<<BH / 512, 512, 0, stream>>>(history, target, td, Wd, bd,
                                            hist, meta, sdist, inv);
    if (useBf16)
        attn_main<true><<<BH / 128, 512, 0, stream>>>(meta, sdist, eh, ehb, tdb,
                                                      W1TB, b1, W2,
                                                      (float*)meta, (float*)sdist);
    else
        attn_main<false><<<BH / 128, 512, 0, stream>>>(meta, sdist, eh, ehb, tdb,
                                                       W1TB, b1, W2,
                                                       (float*)meta, (float*)sdist);
    finalize_kernel<<<B_SZ / 4, 256, 0, stream>>>(inv, (const float*)meta,
                                                  (const float*)sdist, out);
}